// Round 8
// baseline (307.557 us; speedup 1.0000x reference)
//
#include <hip/hip_runtime.h>
#include <math.h>

#define BB     1024
#define CC     256
#define HWN    361
#define SEH    64
#define P3C    768
#define SLICE  (CC * HWN)      // 92416 floats per batch row
#define SLICE4 (SLICE / 4)     // 23104 float4
#define N4TOT  (BB * SLICE4)   // 23,658,496 float4 total
#define CHN    32              // channels per pool block
#define CHF    (CHN * HWN)     // 11552 floats per chunk
#define CHF4   (CHF / 4)       // 2888 float4 (16B-aligned: 32*361*4 % 16 == 0)

typedef float f32x4 __attribute__((ext_vector_type(4)));

// ---- Kernel 1: pool. 8 blocks per b, 32 channels each; LDS transpose. ----
__global__ __launch_bounds__(256) void k_pool(
        const float* __restrict__ x,
        const float* __restrict__ mask,
        const float* __restrict__ msum,
        const float* __restrict__ msqrt,
        float* __restrict__ pooled) {
    __shared__ f32x4 ch4_s[CHF4];          // 46.2 KB chunk
    __shared__ float m_s[HWN];
    float* ch_s = (float*)ch4_s;

    const int t     = threadIdx.x;
    const int b     = blockIdx.x >> 3;
    const int chunk = blockIdx.x & 7;

    for (int i = t; i < HWN; i += 256) m_s[i] = mask[(size_t)b * HWN + i];

    // coalesced float4 stage of 32 channels
    const f32x4* src = (const f32x4*)(x + (size_t)b * SLICE + chunk * CHF);
    #pragma unroll
    for (int it = 0; it < 11; ++it) ch4_s[t + it * 256] = src[t + it * 256];
    if (t < 72) ch4_s[t + 2816] = src[t + 2816];
    __syncthreads();

    // transpose-reduce: 8 lanes per channel
    const int ch = t >> 3, sub = t & 7;
    const float* row = ch_s + ch * HWN;
    float s = 0.0f, mx = -INFINITY;
    for (int k = sub; k < HWN; k += 8) {
        float v = row[k];
        s += v;                                           // raw (unmasked) sum
        mx = fmaxf(mx, fmaf(1.0f - m_s[k], -5000.0f, v));
    }
    #pragma unroll
    for (int off = 4; off; off >>= 1) {                   // reduce within 8 lanes
        s  += __shfl_xor(s, off);
        mx  = fmaxf(mx, __shfl_xor(mx, off));
    }
    if (sub == 0) {
        const float mean   = s / msum[b];
        const float bscale = (msqrt[b] - 14.0f) * 0.1f;   // (sqrt(div)-B_AVG)/10
        const int c = chunk * CHN + ch;
        float* pr = pooled + (size_t)b * P3C;
        pr[c]       = mean;
        pr[256 + c] = mean * bscale;
        pr[512 + c] = mx;
    }
}

// ---- Kernel 2: tiny MLP, 4 b per block (R1-proven) ----
__global__ __launch_bounds__(256) void k_mlp(
        const float* __restrict__ pooled,
        const float* __restrict__ w1,
        const float* __restrict__ b1,
        const float* __restrict__ w2,
        const float* __restrict__ b2,
        float* __restrict__ gb) {
    __shared__ float plds[4 * P3C];
    __shared__ float hlds[4 * SEH];
    const int t  = threadIdx.x;
    const int b0 = blockIdx.x * 4;

    #pragma unroll
    for (int i = 0; i < 12; ++i)
        plds[t + i * 256] = pooled[(size_t)b0 * P3C + t + i * 256];
    __syncthreads();

    {   // layer 1: thread (bb, s)
        const int bb = t >> 6, s = t & 63;
        float acc = b1[s];
        const float* w1r = w1   + s  * P3C;
        const float* pr  = plds + bb * P3C;
        #pragma unroll 8
        for (int j = 0; j < P3C; ++j) acc = fmaf(pr[j], w1r[j], acc);
        hlds[bb * SEH + s] = fmaxf(acc, 0.0f);
    }
    __syncthreads();

    #pragma unroll
    for (int k = 0; k < 8; ++k) {         // layer 2: 2048 dots, 8/thread
        int q  = k * 256 + t;
        int rb = q >> 9;
        int o  = q & 511;
        float a = b2[o];
        const float* w2r = w2   + o  * SEH;
        const float* hr  = hlds + rb * SEH;
        #pragma unroll 8
        for (int ss = 0; ss < SEH; ++ss) a = fmaf(hr[ss], w2r[ss], a);
        int b = b0 + rb;
        if (o < 256) gb[(size_t)b * 512 + o] = 1.0f / (1.0f + __expf(-a));
        else         gb[(size_t)b * 512 + o] = a;
    }
}

// ---- Kernel 3: apply, grid-stride in REVERSE order (L3-tail first) ----
__global__ __launch_bounds__(256) void k_apply(
        const float* __restrict__ x,
        const float* __restrict__ mask,
        const float* __restrict__ gb,
        float* __restrict__ out) {
    const unsigned T = gridDim.x * 256u;
    const f32x4* x4 = (const f32x4*)x;
    f32x4*       o4 = (f32x4*)out;

    for (unsigned i = blockIdx.x * 256u + threadIdx.x; i < (unsigned)N4TOT; i += T) {
        const unsigned idx = (unsigned)(N4TOT - 1) - i;     // reversed stream
        f32x4 v = x4[idx];
        const unsigned b   = idx / SLICE4;                  // magic-mul
        const unsigned rem = idx - b * SLICE4;
        const unsigned e   = rem * 4u;
        const float* gbb = gb   + (size_t)b * 512;
        const float* mb  = mask + (size_t)b * HWN;
        #pragma unroll
        for (int j = 0; j < 4; ++j) {
            unsigned c  = (e + j) / 361u;                   // magic-mul
            unsigned hw = (e + j) - c * 361u;
            v[j] = fmaf(gbb[c], v[j], gbb[256 + c]) * mb[hw];
        }
        __builtin_nontemporal_store(v, &o4[idx]);
    }
}

extern "C" void kernel_launch(void* const* d_in, const int* in_sizes, int n_in,
                              void* d_out, int out_size, void* d_ws, size_t ws_size,
                              hipStream_t stream) {
    const float* x     = (const float*)d_in[0];
    const float* mask  = (const float*)d_in[1];
    const float* msum  = (const float*)d_in[2];
    const float* msqrt = (const float*)d_in[3];
    const float* w1    = (const float*)d_in[4];
    const float* b1    = (const float*)d_in[5];
    const float* w2    = (const float*)d_in[6];
    const float* b2    = (const float*)d_in[7];
    float* out = (float*)d_out;

    float* pooled = (float*)d_ws;                 // B*768 f32 (3 MB)
    float* gb     = pooled + (size_t)BB * P3C;    // B*512 f32 (2 MB)

    k_pool <<<BB * 8, 256, 0, stream>>>(x, mask, msum, msqrt, pooled);
    k_mlp  <<<BB / 4, 256, 0, stream>>>(pooled, w1, b1, w2, b2, gb);
    k_apply<<<4096,   256, 0, stream>>>(x, mask, gb, out);
}

// Round 10
// 304.280 us; speedup vs baseline: 1.0108x; 1.0108x over previous
//
#include <hip/hip_runtime.h>
#include <math.h>

#define BB     1024
#define CC     256
#define HWN    361
#define SEH    64
#define P3C    768
#define SLICE  (CC * HWN)      // 92416 floats per batch row
#define SLICE4 (SLICE / 4)     // 23104 float4 per batch row
#define NBH    512             // batch rows per half (189 MB < 256 MB L3)
#define APB    8               // apply blocks per b
#define SEG4   (SLICE4 / APB)  // 2888 float4 per apply block

typedef float f32x4 __attribute__((ext_vector_type(4)));

// ---- Kernel 1: pool. One wave per (b,c) row; 4 waves/block; fill-shaped. ----
__global__ __launch_bounds__(256) void k_pool(
        const float* __restrict__ x,
        const float* __restrict__ mask,
        const float* __restrict__ msum,
        const float* __restrict__ msqrt,
        float* __restrict__ pooled, int b0) {
    const int wv   = threadIdx.x >> 6;
    const int lane = threadIdx.x & 63;
    const int rid  = blockIdx.x * 4 + wv;
    const int b    = b0 + (rid >> 8);
    const int c    = rid & 255;

    const float* xr = x    + (size_t)b * SLICE + c * HWN;
    const float* mr = mask + (size_t)b * HWN;

    float s = 0.0f, mx = -INFINITY;
    #pragma unroll
    for (int ii = 0; ii < 6; ++ii) {
        const int i = lane + ii * 64;
        if (i < HWN) {
            float v = xr[i];
            s += v;                                       // raw (unmasked) sum
            mx = fmaxf(mx, fmaf(1.0f - mr[i], -5000.0f, v));
        }
    }
    #pragma unroll
    for (int off = 32; off; off >>= 1) {
        s  += __shfl_xor(s, off);
        mx  = fmaxf(mx, __shfl_xor(mx, off));
    }
    if (lane == 0) {
        const float mean   = s / msum[b];
        const float bscale = (msqrt[b] - 14.0f) * 0.1f;   // (sqrt(div)-B_AVG)/10
        float* pr = pooled + (size_t)b * P3C;
        pr[c]       = mean;
        pr[256 + c] = mean * bscale;
        pr[512 + c] = mx;
    }
}

// ---- Kernel 2: tiny MLP, 4 b per block (R1-proven) ----
__global__ __launch_bounds__(256) void k_mlp(
        const float* __restrict__ pooled,
        const float* __restrict__ w1,
        const float* __restrict__ b1,
        const float* __restrict__ w2,
        const float* __restrict__ b2,
        float* __restrict__ gb, int b0) {
    __shared__ float plds[4 * P3C];
    __shared__ float hlds[4 * SEH];
    const int t   = threadIdx.x;
    const int bb0 = b0 + blockIdx.x * 4;

    #pragma unroll
    for (int i = 0; i < 12; ++i)
        plds[t + i * 256] = pooled[(size_t)bb0 * P3C + t + i * 256];
    __syncthreads();

    {   // layer 1: thread (bb, s)
        const int bb = t >> 6, s = t & 63;
        float acc = b1[s];
        const float* w1r = w1   + s  * P3C;
        const float* pr  = plds + bb * P3C;
        #pragma unroll 8
        for (int j = 0; j < P3C; ++j) acc = fmaf(pr[j], w1r[j], acc);
        hlds[bb * SEH + s] = fmaxf(acc, 0.0f);
    }
    __syncthreads();

    #pragma unroll
    for (int k = 0; k < 8; ++k) {         // layer 2: 2048 dots, 8/thread
        int q  = k * 256 + t;
        int rb = q >> 9;
        int o  = q & 511;
        float a = b2[o];
        const float* w2r = w2   + o  * SEH;
        const float* hr  = hlds + rb * SEH;
        #pragma unroll 8
        for (int ss = 0; ss < SEH; ++ss) a = fmaf(hr[ss], w2r[ss], a);
        int b = bb0 + rb;
        if (o < 256) gb[(size_t)b * 512 + o] = 1.0f / (1.0f + __expf(-a));
        else         gb[(size_t)b * 512 + o] = a;
    }
}

// ---- Kernel 3: apply. 8 blocks per b, contiguous segments, forward order. ----
__global__ __launch_bounds__(256) void k_apply(
        const float* __restrict__ x,
        const float* __restrict__ mask,
        const float* __restrict__ gb,
        float* __restrict__ out, int b0) {
    __shared__ float g_s[CC];
    __shared__ float be_s[CC];
    __shared__ float m_s[HWN];

    const int t   = threadIdx.x;
    const int b   = b0 + (blockIdx.x >> 3);
    const int seg = blockIdx.x & 7;

    // 256 threads: each loads one gamma AND one beta (R8 bug: be_s never loaded)
    g_s[t]  = gb[(size_t)b * 512 + t];
    be_s[t] = gb[(size_t)b * 512 + 256 + t];
    for (int i = t; i < HWN; i += 256) m_s[i] = mask[(size_t)b * HWN + i];
    __syncthreads();

    const f32x4* x4 = (const f32x4*)(x   + (size_t)b * SLICE);
    f32x4*       o4 = (f32x4*)      (out + (size_t)b * SLICE);

    auto proc = [&](f32x4& v, int idx) {        // idx = f4 index within b
        const unsigned e0 = (unsigned)idx * 4u;
        #pragma unroll
        for (int j = 0; j < 4; ++j) {
            unsigned e  = e0 + j;
            unsigned c  = e / 361u;             // magic-mul
            unsigned hw = e - c * 361u;
            v[j] = fmaf(g_s[c], v[j], be_s[c]) * m_s[hw];
        }
    };

    int i = seg * SEG4 + t;                      // 2888 f4 = 11*256 + 72
    #pragma unroll 1
    for (int gq = 0; gq < 2; ++gq) {             // 2 groups x 4 deep = 8 iters
        f32x4 v0 = x4[i], v1 = x4[i + 256], v2 = x4[i + 512], v3 = x4[i + 768];
        proc(v0, i); proc(v1, i + 256); proc(v2, i + 512); proc(v3, i + 768);
        __builtin_nontemporal_store(v0, &o4[i]);
        __builtin_nontemporal_store(v1, &o4[i + 256]);
        __builtin_nontemporal_store(v2, &o4[i + 512]);
        __builtin_nontemporal_store(v3, &o4[i + 768]);
        i += 1024;
    }
    {                                            // 3 full iters (8,9,10)
        f32x4 v0 = x4[i], v1 = x4[i + 256], v2 = x4[i + 512];
        proc(v0, i); proc(v1, i + 256); proc(v2, i + 512);
        __builtin_nontemporal_store(v0, &o4[i]);
        __builtin_nontemporal_store(v1, &o4[i + 256]);
        __builtin_nontemporal_store(v2, &o4[i + 512]);
        i += 768;
    }
    if (t < 72) {                                // partial iter (72 f4)
        f32x4 v = x4[i];
        proc(v, i);
        __builtin_nontemporal_store(v, &o4[i]);
    }
}

extern "C" void kernel_launch(void* const* d_in, const int* in_sizes, int n_in,
                              void* d_out, int out_size, void* d_ws, size_t ws_size,
                              hipStream_t stream) {
    const float* x     = (const float*)d_in[0];
    const float* mask  = (const float*)d_in[1];
    const float* msum  = (const float*)d_in[2];
    const float* msqrt = (const float*)d_in[3];
    const float* w1    = (const float*)d_in[4];
    const float* b1    = (const float*)d_in[5];
    const float* w2    = (const float*)d_in[6];
    const float* b2    = (const float*)d_in[7];
    float* out = (float*)d_out;

    float* pooled = (float*)d_ws;                 // B*768 f32 (3 MB)
    float* gb     = pooled + (size_t)BB * P3C;    // B*512 f32 (2 MB)

    for (int h = 0; h < 2; ++h) {
        const int b0 = h * NBH;
        k_pool <<<NBH * CC / 4, 256, 0, stream>>>(x, mask, msum, msqrt, pooled, b0);
        k_mlp  <<<NBH / 4,      256, 0, stream>>>(pooled, w1, b1, w2, b2, gb, b0);
        k_apply<<<NBH * APB,    256, 0, stream>>>(x, mask, gb, out, b0);
    }
}

// Round 11
// 275.997 us; speedup vs baseline: 1.1143x; 1.1025x over previous
//
#include <hip/hip_runtime.h>
#include <hip/hip_fp16.h>
#include <math.h>

#define BB     1024
#define CC     256
#define HWN    361
#define SEH    64
#define P3C    768
#define SLICE  (CC * HWN)      // 92416 floats per batch row
#define SLICE4 (SLICE / 4)     // 23104 float4
#define SLICE8 (SLICE / 8)     // 11552 f16x8
#define NW     16

typedef float    f32x4 __attribute__((ext_vector_type(4)));
typedef _Float16 f16x8 __attribute__((ext_vector_type(8)));

// One block (16 waves) per batch row b; 2 blocks/CU (VGPR<=64).
// USE_F16WS: pool phase writes an fp16 copy of x[b] to ws; apply re-reads
// 189 MB of f16 (L3-resident) instead of 378 MB of f32.
template <bool USE_F16WS>
__global__ __launch_bounds__(1024, 8) void k_se_fused(
        const float* __restrict__ x,
        const float* __restrict__ mask,
        const float* __restrict__ msum,
        const float* __restrict__ msqrt,
        const float* __restrict__ w1,
        const float* __restrict__ b1,
        const float* __restrict__ w2,
        const float* __restrict__ b2,
        float* __restrict__ out,
        _Float16* __restrict__ ws) {
    __shared__ float m_s[HWN];
    __shared__ float p_s[P3C];
    __shared__ float part_s[NW * SEH];
    __shared__ float hid_s[SEH];
    __shared__ float g_s[CC];
    __shared__ float be_s[CC];

    const int tid  = threadIdx.x;
    const int lane = tid & 63;
    const int wv   = tid >> 6;
    const int b    = blockIdx.x;

    const float* xb  = x  + (size_t)b * SLICE;
    _Float16*    wsb = ws + (size_t)b * SLICE;

    if (tid < HWN) m_s[tid] = mask[(size_t)b * HWN + tid];
    __syncthreads();

    const float inv_div = 1.0f / msum[b];
    const float bscale  = (msqrt[b] - 14.0f) * 0.1f;   // (sqrt(div)-B_AVG)/10

    // ---- pool (+ fp16 copy): wave wv owns rows wv*16 .. wv*16+15 ----
    for (int k = 0; k < 16; ++k) {
        const int c = wv * 16 + k;
        const float* xr = xb + c * HWN;
        _Float16*    wr = wsb + c * HWN;
        float s = 0.0f, mx = -INFINITY;
        #pragma unroll
        for (int ii = 0; ii < 6; ++ii) {
            const int i = lane + ii * 64;
            if (i < HWN) {
                float v = xr[i];
                if (USE_F16WS) wr[i] = (_Float16)v;
                s += v;                                    // raw (unmasked) sum
                mx = fmaxf(mx, fmaf(1.0f - m_s[i], -5000.0f, v));
            }
        }
        #pragma unroll
        for (int off = 32; off; off >>= 1) {
            s  += __shfl_xor(s, off);
            mx  = fmaxf(mx, __shfl_xor(mx, off));
        }
        if (lane == 0) {
            float mean = s * inv_div;
            p_s[c]       = mean;
            p_s[256 + c] = mean * bscale;
            p_s[512 + c] = mx;
        }
    }
    __syncthreads();

    // ---- layer 1 (768 -> 64): 16 partials (48 long) per output ----
    {
        const int q = tid >> 6, s = tid & 63;
        const float* w1r = w1  + s * P3C + q * 48;
        const float* pp  = p_s + q * 48;
        float acc = 0.0f;
        #pragma unroll 8
        for (int j = 0; j < 48; ++j) acc = fmaf(pp[j], w1r[j], acc);
        part_s[q * SEH + s] = acc;
    }
    __syncthreads();
    if (tid < SEH) {
        float h = b1[tid];
        #pragma unroll
        for (int q = 0; q < NW; ++q) h += part_s[q * SEH + tid];
        hid_s[tid] = fmaxf(h, 0.0f);
    }
    __syncthreads();

    // ---- layer 2 (64 -> 512) ----
    if (tid < 512) {
        float a = b2[tid];
        const float* w2r = w2 + (size_t)tid * SEH;
        #pragma unroll 8
        for (int ss = 0; ss < SEH; ++ss) a = fmaf(hid_s[ss], w2r[ss], a);
        if (tid < 256) g_s[tid]        = 1.0f / (1.0f + __expf(-a));
        else           be_s[tid - 256] = a;
    }
    __syncthreads();

    // ---- apply ----
    f32x4* o4 = (f32x4*)(out + (size_t)b * SLICE);
    if (USE_F16WS) {
        const f16x8* w8 = (const f16x8*)wsb;
        for (int i = tid; i < SLICE8; i += 1024) {
            f16x8 hv = w8[i];
            const unsigned e0 = (unsigned)i * 8u;
            f32x4 r0, r1;
            #pragma unroll
            for (int j = 0; j < 4; ++j) {
                unsigned e  = e0 + j;
                unsigned c  = e / 361u;           // magic-mul
                unsigned hw = e - c * 361u;
                r0[j] = fmaf(g_s[c], (float)hv[j], be_s[c]) * m_s[hw];
            }
            #pragma unroll
            for (int j = 4; j < 8; ++j) {
                unsigned e  = e0 + j;
                unsigned c  = e / 361u;
                unsigned hw = e - c * 361u;
                r1[j - 4] = fmaf(g_s[c], (float)hv[j], be_s[c]) * m_s[hw];
            }
            __builtin_nontemporal_store(r0, &o4[i * 2]);
            __builtin_nontemporal_store(r1, &o4[i * 2 + 1]);
        }
    } else {
        const f32x4* x4 = (const f32x4*)xb;
        for (int i = tid; i < SLICE4; i += 1024) {
            f32x4 v = x4[i];
            const unsigned e0 = (unsigned)i * 4u;
            #pragma unroll
            for (int j = 0; j < 4; ++j) {
                unsigned e  = e0 + j;
                unsigned c  = e / 361u;
                unsigned hw = e - c * 361u;
                v[j] = fmaf(g_s[c], v[j], be_s[c]) * m_s[hw];
            }
            __builtin_nontemporal_store(v, &o4[i]);
        }
    }
}

extern "C" void kernel_launch(void* const* d_in, const int* in_sizes, int n_in,
                              void* d_out, int out_size, void* d_ws, size_t ws_size,
                              hipStream_t stream) {
    const float* x     = (const float*)d_in[0];
    const float* mask  = (const float*)d_in[1];
    const float* msum  = (const float*)d_in[2];
    const float* msqrt = (const float*)d_in[3];
    const float* w1    = (const float*)d_in[4];
    const float* b1    = (const float*)d_in[5];
    const float* w2    = (const float*)d_in[6];
    const float* b2    = (const float*)d_in[7];
    float* out = (float*)d_out;
    _Float16* ws = (_Float16*)d_ws;

    const size_t need = (size_t)BB * SLICE * sizeof(_Float16);   // 189 MB
    if (ws_size >= need) {
        k_se_fused<true><<<BB, 1024, 0, stream>>>(x, mask, msum, msqrt,
                                                  w1, b1, w2, b2, out, ws);
    } else {
        k_se_fused<false><<<BB, 1024, 0, stream>>>(x, mask, msum, msqrt,
                                                   w1, b1, w2, b2, out, ws);
    }
}

// Round 12
// 209.275 us; speedup vs baseline: 1.4696x; 1.3188x over previous
//
#include <hip/hip_runtime.h>
#include <math.h>

#define BB     1024
#define CC     256
#define HWN    361
#define SEH    64
#define P3C    768
#define SLICE  (CC * HWN)      // 92416 floats per batch row
#define NW     16

typedef _Float16 f16x2 __attribute__((ext_vector_type(2)));

// pack two f32 into one VGPR as 2xf16 (RNE via scalar casts)
__device__ __forceinline__ unsigned pack2(float a, float b) {
    f16x2 h;
    h[0] = (_Float16)a;
    h[1] = (_Float16)b;
    return __builtin_bit_cast(unsigned, h);
}

// One block (16 waves) per batch row b; 1 block/CU (VGPR cap 128).
// Pool loads x[b] once, packs it to f16 pairs PINNED in VGPRs (48 regs/lane),
// reduces sum/max from the f32 values. After the in-LDS MLP, apply unpacks
// from registers and stores -- x is never re-read from any cache level.
__global__ __launch_bounds__(1024, 4) void k_se_fused(
        const float* __restrict__ x,
        const float* __restrict__ mask,
        const float* __restrict__ msum,
        const float* __restrict__ msqrt,
        const float* __restrict__ w1,
        const float* __restrict__ b1,
        const float* __restrict__ w2,
        const float* __restrict__ b2,
        float* __restrict__ out) {
    __shared__ float m_s[HWN];
    __shared__ float p_s[P3C];
    __shared__ float part_s[NW * SEH];
    __shared__ float hid_s[SEH];
    __shared__ float g_s[CC];
    __shared__ float be_s[CC];

    const int tid  = threadIdx.x;
    const int lane = tid & 63;
    const int wv   = tid >> 6;          // 0..15
    const int b    = blockIdx.x;

    const float* xb = x + (size_t)b * SLICE;

    if (tid < HWN) m_s[tid] = mask[(size_t)b * HWN + tid];
    __syncthreads();

    const float inv_div = 1.0f / msum[b];
    const float bscale  = (msqrt[b] - 14.0f) * 0.1f;   // (sqrt(div)-B_AVG)/10

    // 361 = 5*64 + 41: per lane 6 values/row (6th valid for lane<41)
    const int  i5    = lane + 320;
    const int  a5    = (i5 < HWN) ? i5 : (HWN - 1);    // clamped tail addr
    const bool tail  = (lane < 41);

    unsigned pk[16][3];                 // packed f16 payload, statically indexed

    // ---- pool + pack: 2 rows per pass ----
    #pragma unroll
    for (int k = 0; k < 16; k += 2) {
        const int c0 = wv * 16 + k;
        const float* r0 = xb + c0 * HWN;
        const float* r1 = r0 + HWN;
        float v[6], w[6];
        #pragma unroll
        for (int ii = 0; ii < 5; ++ii) {
            v[ii] = r0[lane + ii * 64];
            w[ii] = r1[lane + ii * 64];
        }
        v[5] = r0[a5];
        w[5] = r1[a5];

        pk[k][0]     = pack2(v[0], v[1]);
        pk[k][1]     = pack2(v[2], v[3]);
        pk[k][2]     = pack2(v[4], v[5]);
        pk[k + 1][0] = pack2(w[0], w[1]);
        pk[k + 1][1] = pack2(w[2], w[3]);
        pk[k + 1][2] = pack2(w[4], w[5]);
        // pin: opaque to DCE/remat; survives barriers in VGPRs
        asm volatile("" : "+v"(pk[k][0]), "+v"(pk[k][1]), "+v"(pk[k][2]),
                          "+v"(pk[k+1][0]), "+v"(pk[k+1][1]), "+v"(pk[k+1][2]));

        float s0 = 0.0f, s1 = 0.0f, x0 = -INFINITY, x1 = -INFINITY;
        #pragma unroll
        for (int ii = 0; ii < 5; ++ii) {
            const float pen = (1.0f - m_s[lane + ii * 64]) * -5000.0f;
            s0 += v[ii];  x0 = fmaxf(x0, v[ii] + pen);
            s1 += w[ii];  x1 = fmaxf(x1, w[ii] + pen);
        }
        if (tail) {
            const float pen = (1.0f - m_s[i5]) * -5000.0f;
            s0 += v[5];   x0 = fmaxf(x0, v[5] + pen);
            s1 += w[5];   x1 = fmaxf(x1, w[5] + pen);
        }
        #pragma unroll
        for (int off = 32; off; off >>= 1) {
            s0 += __shfl_xor(s0, off);  x0 = fmaxf(x0, __shfl_xor(x0, off));
            s1 += __shfl_xor(s1, off);  x1 = fmaxf(x1, __shfl_xor(x1, off));
        }
        if (lane == 0) {
            const float mean0 = s0 * inv_div, mean1 = s1 * inv_div;
            p_s[c0]           = mean0;
            p_s[256 + c0]     = mean0 * bscale;
            p_s[512 + c0]     = x0;
            p_s[c0 + 1]       = mean1;
            p_s[256 + c0 + 1] = mean1 * bscale;
            p_s[512 + c0 + 1] = x1;
        }
    }
    __syncthreads();

    // ---- layer 1 (768 -> 64): 16 partials (48 long) per output ----
    {
        const int q = tid >> 6, s = tid & 63;
        const float* w1r = w1  + s * P3C + q * 48;
        const float* pp  = p_s + q * 48;
        float acc = 0.0f;
        #pragma unroll 8
        for (int j = 0; j < 48; ++j) acc = fmaf(pp[j], w1r[j], acc);
        part_s[q * SEH + s] = acc;
    }
    __syncthreads();
    if (tid < SEH) {
        float h = b1[tid];
        #pragma unroll
        for (int q = 0; q < NW; ++q) h += part_s[q * SEH + tid];
        hid_s[tid] = fmaxf(h, 0.0f);
    }
    __syncthreads();

    // ---- layer 2 (64 -> 512) ----
    if (tid < 512) {
        float a = b2[tid];
        const float* w2r = w2 + (size_t)tid * SEH;
        #pragma unroll 8
        for (int ss = 0; ss < SEH; ++ss) a = fmaf(hid_s[ss], w2r[ss], a);
        if (tid < 256) g_s[tid]        = 1.0f / (1.0f + __expf(-a));
        else           be_s[tid - 256] = a;
    }
    __syncthreads();

    // ---- apply from pinned registers; zero reads ----
    float* ob = out + (size_t)b * SLICE;
    #pragma unroll
    for (int k = 0; k < 16; ++k) {
        const int c  = wv * 16 + k;
        const float g  = g_s[c];
        const float be = be_s[c];
        float* orow = ob + c * HWN;
        const f16x2 h0 = __builtin_bit_cast(f16x2, pk[k][0]);
        const f16x2 h1 = __builtin_bit_cast(f16x2, pk[k][1]);
        const f16x2 h2 = __builtin_bit_cast(f16x2, pk[k][2]);
        orow[lane]       = fmaf(g, (float)h0[0], be) * m_s[lane];
        orow[lane + 64]  = fmaf(g, (float)h0[1], be) * m_s[lane + 64];
        orow[lane + 128] = fmaf(g, (float)h1[0], be) * m_s[lane + 128];
        orow[lane + 192] = fmaf(g, (float)h1[1], be) * m_s[lane + 192];
        orow[lane + 256] = fmaf(g, (float)h2[0], be) * m_s[lane + 256];
        if (tail)
            orow[i5]     = fmaf(g, (float)h2[1], be) * m_s[i5];
    }
}

extern "C" void kernel_launch(void* const* d_in, const int* in_sizes, int n_in,
                              void* d_out, int out_size, void* d_ws, size_t ws_size,
                              hipStream_t stream) {
    const float* x     = (const float*)d_in[0];
    const float* mask  = (const float*)d_in[1];
    const float* msum  = (const float*)d_in[2];
    const float* msqrt = (const float*)d_in[3];
    const float* w1    = (const float*)d_in[4];
    const float* b1    = (const float*)d_in[5];
    const float* w2    = (const float*)d_in[6];
    const float* b2    = (const float*)d_in[7];
    float* out = (float*)d_out;

    k_se_fused<<<BB, 1024, 0, stream>>>(x, mask, msum, msqrt, w1, b1, w2, b2, out);
}